// Round 12
// baseline (223.129 us; speedup 1.0000x reference)
//
#include <hip/hip_runtime.h>
#include <cmath>

// ---------------------------------------------------------------------------
// T5 MHSA: x->(QKV proj, f16 MFMA GEMM) -> flash attn w/ T5 bias -> out proj
// All matmuls on MFMA. fp16 intermediates, fp32 accum.
// ---------------------------------------------------------------------------

typedef _Float16 f16x8 __attribute__((ext_vector_type(8)));
typedef _Float16 f16x4 __attribute__((ext_vector_type(4)));
typedef float    f32x4 __attribute__((ext_vector_type(4)));

#define NEG_INF (-__builtin_inff())
#define LOG2E 1.4426950408889634f

#if __has_builtin(__builtin_amdgcn_exp2f)
#define EXP2(x) __builtin_amdgcn_exp2f(x)
#else
#define EXP2(x) exp2f(x)
#endif

__device__ __forceinline__ void gl_lds16(const void* g, void* l) {
  __builtin_amdgcn_global_load_lds(
      (__attribute__((address_space(1))) void*)g,
      (__attribute__((address_space(3))) void*)l,
      16, 0, 0);
}

__device__ __forceinline__ f32x4 mfma32(f16x8 a, f16x8 b, f32x4 c) {
  return __builtin_amdgcn_mfma_f32_16x16x32_f16(a, b, c, 0, 0, 0);
}
__device__ __forceinline__ f32x4 mfma16(f16x4 a, f16x4 b, f32x4 c) {
  return __builtin_amdgcn_mfma_f32_16x16x16f16(a, b, c, 0, 0, 0);
}

typedef __attribute__((address_space(3))) _Float16* lds_f16p;

#define DSR(d, a, o) \
  asm volatile("ds_read_b128 %0, %1 offset:" o : "=v"(d) : "v"(a))
#define DSR64(d, a, o) \
  asm volatile("ds_read_b64 %0, %1 offset:" o : "=v"(d) : "v"(a))
#define LGKM0                                          \
  asm volatile("s_waitcnt lgkmcnt(0)" ::: "memory");   \
  __builtin_amdgcn_sched_barrier(0)

// -------------------------------- convert ---------------------------------
// single launch for all 4 fp32->fp16 conversions (saves 3 launch gaps)
__global__ void cvt4_kernel(const float* __restrict__ x,
                            const float* __restrict__ w1,
                            const float* __restrict__ w2,
                            const float* __restrict__ w3,
                            _Float16* __restrict__ ox, _Float16* __restrict__ o1,
                            _Float16* __restrict__ o2, _Float16* __restrict__ o3) {
  const int bid = blockIdx.x;
  const float* src;
  _Float16* dst;
  int idx;
  if (bid < 8192) {
    src = x; dst = ox; idx = bid * 256 + threadIdx.x;
  } else if (bid < 10240) {
    src = w1; dst = o1; idx = (bid - 8192) * 256 + threadIdx.x;
  } else if (bid < 11264) {
    src = w2; dst = o2; idx = (bid - 10240) * 256 + threadIdx.x;
  } else {
    src = w3; dst = o3; idx = (bid - 11264) * 256 + threadIdx.x;
  }
  float4 v = reinterpret_cast<const float4*>(src)[idx];
  f16x4 o;
  o[0] = (_Float16)v.x; o[1] = (_Float16)v.y;
  o[2] = (_Float16)v.z; o[3] = (_Float16)v.w;
  reinterpret_cast<f16x4*>(dst)[idx] = o;
}

// --------------------------------- GEMM -----------------------------------
// C = A(MxK) * Bm(NxK)^T.  128x128 tile, BK=32, 4 waves (2x2 of 64x64).
// 3-deep pipeline (R10 best config, 96.6us): triple-buffer LDS; stage tile
// s+2 during compute of tile s; counted vmcnt(8) keeps 2 tiles in flight
// across raw s_barriers. asm ds_read keeps the loop waitcnt-opaque. LDS
// chunk-XOR swizzle keeps ds_read conflict-free.
#define GEMM_VM8 asm volatile("s_waitcnt vmcnt(8)" ::: "memory")
#define GEMM_VM4 asm volatile("s_waitcnt vmcnt(4)" ::: "memory")
#define GEMM_VM0 asm volatile("s_waitcnt vmcnt(0)" ::: "memory")
#define GEMM_BAR __builtin_amdgcn_s_barrier()

#define GEMM_STAGE(buf, kk)                         \
  do {                                              \
    gl_lds16(pA0 + (kk), &lds_a[buf][wofs]);        \
    gl_lds16(pA1 + (kk), &lds_a[buf][2048 + wofs]); \
    gl_lds16(pB0 + (kk), &lds_b[buf][wofs]);        \
    gl_lds16(pB1 + (kk), &lds_b[buf][2048 + wofs]); \
  } while (0)

#define GEMM_COMPUTE(aB, bB)                             \
  do {                                                   \
    f16x8 af0, af1, af2, af3, bf0, bf1, bf2, bf3;        \
    DSR(af0, aB, "0");                                   \
    DSR(bf0, bB, "0");                                   \
    DSR(af1, aB, "1024");                                \
    DSR(bf1, bB, "1024");                                \
    DSR(af2, aB, "2048");                                \
    DSR(bf2, bB, "2048");                                \
    DSR(af3, aB, "3072");                                \
    DSR(bf3, bB, "3072");                                \
    asm volatile("s_waitcnt lgkmcnt(4)" ::: "memory");   \
    __builtin_amdgcn_sched_barrier(0);                   \
    __builtin_amdgcn_s_setprio(1);                       \
    acc[0][0] = mfma32(af0, bf0, acc[0][0]);             \
    acc[0][1] = mfma32(af0, bf1, acc[0][1]);             \
    acc[1][0] = mfma32(af1, bf0, acc[1][0]);             \
    acc[1][1] = mfma32(af1, bf1, acc[1][1]);             \
    asm volatile("s_waitcnt lgkmcnt(0)" ::: "memory");   \
    __builtin_amdgcn_sched_barrier(0);                   \
    acc[0][2] = mfma32(af0, bf2, acc[0][2]);             \
    acc[0][3] = mfma32(af0, bf3, acc[0][3]);             \
    acc[1][2] = mfma32(af1, bf2, acc[1][2]);             \
    acc[1][3] = mfma32(af1, bf3, acc[1][3]);             \
    acc[2][0] = mfma32(af2, bf0, acc[2][0]);             \
    acc[2][1] = mfma32(af2, bf1, acc[2][1]);             \
    acc[2][2] = mfma32(af2, bf2, acc[2][2]);             \
    acc[2][3] = mfma32(af2, bf3, acc[2][3]);             \
    acc[3][0] = mfma32(af3, bf0, acc[3][0]);             \
    acc[3][1] = mfma32(af3, bf1, acc[3][1]);             \
    acc[3][2] = mfma32(af3, bf2, acc[3][2]);             \
    acc[3][3] = mfma32(af3, bf3, acc[3][3]);             \
    __builtin_amdgcn_s_setprio(0);                       \
  } while (0)

template <int MODE>
__global__ __launch_bounds__(256, 3) void gemm_kernel(
    const _Float16* __restrict__ A, const _Float16* __restrict__ Bm,
    int M, int N, int K,
    const float* __restrict__ bias_q, const float* __restrict__ bias_v,
    _Float16* __restrict__ qkbuf, _Float16* __restrict__ vtbuf,
    const float* __restrict__ bias_o, float* __restrict__ outf) {
  __shared__ __align__(16) _Float16 lds_a[3][128 * 32];
  __shared__ __align__(16) _Float16 lds_b[3][128 * 32];
  const int t = threadIdx.x;
  const int w = t >> 6;
  const int lane = t & 63;
  const int lq = lane & 15, lg = lane >> 4;
  const int wr = w >> 1, wc = w & 1;
  const int m0 = blockIdx.y * 128, n0 = blockIdx.x * 128;

  const int stc = ((t & 3) ^ ((t >> 3) & 3)) * 8;
  const _Float16* pA0 = A + (size_t)(m0 + (t >> 2)) * K + stc;
  const _Float16* pA1 = pA0 + (size_t)64 * K;
  const _Float16* pB0 = Bm + (size_t)(n0 + (t >> 2)) * K + stc;
  const _Float16* pB1 = pB0 + (size_t)64 * K;
  const int wofs = w * 512;

  const int xsw = (lq >> 1) & 3;
  const uint32_t aB0 = (uint32_t)(uintptr_t)(lds_f16p)&lds_a[0][0] +
                       (uint32_t)((wr * 64 + lq) * 64 + ((lg ^ xsw) << 4));
  const uint32_t aB1 = aB0 + 8192;
  const uint32_t aB2 = aB0 + 16384;
  const uint32_t bB0 = (uint32_t)(uintptr_t)(lds_f16p)&lds_b[0][0] +
                       (uint32_t)((wc * 64 + lq) * 64 + ((lg ^ xsw) << 4));
  const uint32_t bB1 = bB0 + 8192;
  const uint32_t bB2 = bB0 + 16384;

  f32x4 acc[4][4];
#pragma unroll
  for (int mi = 0; mi < 4; ++mi)
#pragma unroll
    for (int ni = 0; ni < 4; ++ni) acc[mi][ni] = (f32x4){0.f, 0.f, 0.f, 0.f};

  GEMM_STAGE(0, 0);
  GEMM_STAGE(1, 32);
  for (int kt = 0; kt + 160 <= K; kt += 96) {
    GEMM_STAGE(2, kt + 64);
    GEMM_VM8;
    GEMM_BAR;
    GEMM_COMPUTE(aB0, bB0);
    GEMM_BAR;
    GEMM_STAGE(0, kt + 96);
    GEMM_VM8;
    GEMM_BAR;
    GEMM_COMPUTE(aB1, bB1);
    GEMM_BAR;
    GEMM_STAGE(1, kt + 128);
    GEMM_VM8;
    GEMM_BAR;
    GEMM_COMPUTE(aB2, bB2);
    GEMM_BAR;
  }
  GEMM_VM4;
  GEMM_BAR;
  GEMM_COMPUTE(aB0, bB0);
  GEMM_BAR;
  GEMM_VM0;
  GEMM_BAR;
  GEMM_COMPUTE(aB1, bB1);

  if (MODE == 0) {
    const bool isqk = (n0 < 2048);
#pragma unroll
    for (int mi = 0; mi < 4; ++mi)
#pragma unroll
      for (int ni = 0; ni < 4; ++ni)
#pragma unroll
        for (int r = 0; r < 4; ++r) {
          const int mg = m0 + wr * 64 + mi * 16 + lg * 4 + r;
          const int ng = n0 + wc * 64 + ni * 16 + lq;
          const int bb = mg >> 10, ii = mg & 1023;
          float val = acc[mi][ni][r];
          if (isqk) {
            val += bias_q[ng];
            const int hh = ng >> 7, cc = ng & 127;
            qkbuf[((size_t)((bb * 16 + hh) * 1024 + ii)) * 128 + cc] =
                (_Float16)val;
          } else {
            const int nn = ng - 2048;
            val += bias_v[nn];
            const int hh = nn >> 6, dv = nn & 63;
            vtbuf[((size_t)((bb * 16 + hh) * 64 + dv)) * 1024 + ii] =
                (_Float16)val;
          }
        }
  } else {
#pragma unroll
    for (int mi = 0; mi < 4; ++mi)
#pragma unroll
      for (int ni = 0; ni < 4; ++ni)
#pragma unroll
        for (int r = 0; r < 4; ++r) {
          const int mg = m0 + wr * 64 + mi * 16 + lg * 4 + r;
          const int ng = n0 + wc * 64 + ni * 16 + lq;
          outf[(size_t)mg * N + ng] = acc[mi][ni][r] + bias_o[ng];
        }
  }
}

// ------------------------------- attention --------------------------------
// Block = 4 waves, owns q-tile PAIR (tA=b4, tB=15-b4) of one (b,h): constant
// work per block. K/V tiles (KVBLK=64) staged in LDS, double-buffered with
// COUNTED vmcnt(4) + raw s_barrier (R8 GEMM recipe): the next tile's 4
// global_load_lds stay in flight across the barrier instead of being drained
// by __syncthreads. All in-loop LDS reads are inline-asm ds_read (+ lgkmcnt0
// + sched_barrier fences), keeping the loop waitcnt-opaque. V fragment reads
// are issued BEFORE softmax so their latency hides under the VALU phase.
__device__ __forceinline__ void stage_kv(const _Float16* __restrict__ kb,
                                         const _Float16* __restrict__ vtb,
                                         int j0, _Float16* kl, _Float16* vl,
                                         int t) {
  const int r0 = t >> 3, c0 = t & 7;
  const int r1 = r0 + 32;
  const int kc0 = c0 ^ (r0 & 7), kc1 = c0 ^ (r1 & 7);
  gl_lds16(kb + (size_t)(j0 + r0) * 128 + kc0 * 8, kl + t * 8);
  gl_lds16(kb + (size_t)(j0 + r1) * 128 + kc1 * 8, kl + (t + 256) * 8);
  gl_lds16(vtb + (size_t)r0 * 1024 + j0 + kc0 * 8, vl + t * 8);
  gl_lds16(vtb + (size_t)r1 * 1024 + j0 + kc1 * 8, vl + (t + 256) * 8);
}

__device__ __forceinline__ void softmax16(f32x4 (&st)[4], f16x4 (&ph)[4],
                                          int qi, int j0, bool far,
                                          const float* __restrict__ tab,
                                          float t128, int lg4, float& m_run,
                                          float& l_part, f32x4 (&oacc)[4]) {
  float xs[16];
  float lmax = NEG_INF;
  if (far) {
#pragma unroll
    for (int js = 0; js < 4; ++js)
#pragma unroll
      for (int r = 0; r < 4; ++r) {
        const float xv = fmaf(st[js][r], 0.125f * LOG2E, t128);
        xs[js * 4 + r] = xv;
        lmax = fmaxf(lmax, xv);
      }
  } else {
#pragma unroll
    for (int js = 0; js < 4; ++js)
#pragma unroll
      for (int r = 0; r < 4; ++r) {
        const int jj = j0 + js * 16 + lg4 + r;
        const int dd = qi - jj;
        const int idx = dd < 0 ? 0 : (dd > 128 ? 128 : dd);
        const float xv =
            (dd < 0) ? NEG_INF : fmaf(st[js][r], 0.125f * LOG2E, tab[idx]);
        xs[js * 4 + r] = xv;
        lmax = fmaxf(lmax, xv);
      }
  }
  if (__any(lmax > m_run + 8.0f)) {
    float tmax = fmaxf(lmax, __shfl_xor(lmax, 16));
    tmax = fmaxf(tmax, __shfl_xor(tmax, 32));
    const float m_new = fmaxf(m_run, tmax);
    const float sf = EXP2(m_run - m_new);
    m_run = m_new;
    l_part *= sf;
    f32x4 sfv;
#pragma unroll
    for (int r = 0; r < 4; ++r) sfv[r] = __shfl(sf, lg4 + r);
#pragma unroll
    for (int db = 0; db < 4; ++db) oacc[db] *= sfv;
  }
  float ls = 0.f;
#pragma unroll
  for (int js = 0; js < 4; ++js)
#pragma unroll
    for (int r = 0; r < 4; ++r) {
      const float p = EXP2(xs[js * 4 + r] - m_run);
      ls += p;
      ph[js][r] = (_Float16)p;
    }
  l_part += ls;
}

__global__ __launch_bounds__(256, 4) void attn_kernel(
    const _Float16* __restrict__ qk,  // [B*H][1024][128] (q | k)
    const _Float16* __restrict__ vt,  // [B*H][64][1024]  (V^T)
    const float* __restrict__ bias,   // [32][16]
    _Float16* __restrict__ ao) {      // [B][1024][H*64]
  __shared__ __align__(16) _Float16 kls[2][64 * 64];
  __shared__ __align__(16) _Float16 vls[2][64 * 64];
  __shared__ float tab[132];
  const int t = threadIdx.x;
  const int bid = blockIdx.x;
  const int bh = (bid & 7) * 16 + (bid >> 6);
  const int b4 = (bid >> 3) & 7;
  const int h = bh & 15, b = bh >> 4;
  if (t < 129) {
    const int bucket =
        (t <= 16) ? t : 16 + (int)(log((double)(t - 15)) * 15.0 / log(113.0));
    tab[t] = bias[bucket * 16 + h] * LOG2E;
  }

  const int w = t >> 6, lane = t & 63;
  const int lq = lane & 15, lg = lane >> 4;
  const int lg4 = lg * 4, lg8 = lg * 8;
  const int tA = b4, tB = 15 - b4;
  const int q0A = tA * 64 + w * 16, q0B = tB * 64 + w * 16;
  const int qA = q0A + lq, qB = q0B + lq;
  const _Float16* qkb = qk + (size_t)bh * 1024 * 128;
  const _Float16* kb = qkb + 64;
  const _Float16* vtb = vt + (size_t)bh * 64 * 1024;

  const f16x8 qfA0 = *(const f16x8*)&qkb[qA * 128 + lg8];
  const f16x8 qfA1 = *(const f16x8*)&qkb[qA * 128 + 32 + lg8];
  const f16x8 qfB0 = *(const f16x8*)&qkb[qB * 128 + lg8];
  const f16x8 qfB1 = *(const f16x8*)&qkb[qB * 128 + 32 + lg8];

  f32x4 oA[4], oB[4];
#pragma unroll
  for (int db = 0; db < 4; ++db) {
    oA[db] = (f32x4){0.f, 0.f, 0.f, 0.f};
    oB[db] = (f32x4){0.f, 0.f, 0.f, 0.f};
  }
  float mA = NEG_INF, lAp = 0.f, mB = NEG_INF, lBp = 0.f;

  stage_kv(kb, vtb, 0, kls[0], vls[0], t);
  __syncthreads();  // tab + first tile (one-time drain)
  const float t128 = tab[128];
  const int krsw = lq & 7;
  const int vsw = (lq & 7) << 1;

  // LDS byte addresses for asm ds_read (per-lane, swizzled)
  const uint32_t kbase = (uint32_t)(uintptr_t)(lds_f16p)&kls[0][0];
  const uint32_t vbase = (uint32_t)(uintptr_t)(lds_f16p)&vls[0][0];
  const uint32_t ka0b = kbase + (uint32_t)(lq * 128 + ((lg ^ krsw) << 4));
  const uint32_t ka1b = kbase + (uint32_t)(lq * 128 + (((lg + 4) ^ krsw) << 4));
  const uint32_t va0b = vbase + (uint32_t)(lq * 128 + ((lg ^ vsw) << 3));
  const uint32_t va1b = vbase + (uint32_t)(lq * 128 + (((4 + lg) ^ vsw) << 3));
  const uint32_t va2b = vbase + (uint32_t)(lq * 128 + (((8 + lg) ^ vsw) << 3));
  const uint32_t va3b = vbase + (uint32_t)(lq * 128 + (((12 + lg) ^ vsw) << 3));

  int cur = 0;
  for (int jt = 0; jt <= tB; ++jt) {
    const int j0 = jt * 64;
    if (jt < tB) {
      stage_kv(kb, vtb, j0 + 64, kls[cur ^ 1], vls[cur ^ 1], t);
      asm volatile("s_waitcnt vmcnt(4)" ::: "memory");  // tile jt landed
    } else {
      asm volatile("s_waitcnt vmcnt(0)" ::: "memory");
    }
    __builtin_amdgcn_s_barrier();
    const bool aact = (jt <= tA);
    const uint32_t co = cur ? 8192u : 0u;
    const uint32_t ka0 = ka0b + co, ka1 = ka1b + co;
    const uint32_t va0 = va0b + co, va1 = va1b + co, va2 = va2b + co,
                   va3 = va3b + co;

    // K fragments (asm b128): kf0/kf1 per js (js offset = js*2048 bytes)
    f16x8 kf0[4], kf1[4];
    DSR(kf0[0], ka0, "0");
    DSR(kf1[0], ka1, "0");
    DSR(kf0[1], ka0, "2048");
    DSR(kf1[1], ka1, "2048");
    DSR(kf0[2], ka0, "4096");
    DSR(kf1[2], ka1, "4096");
    DSR(kf0[3], ka0, "6144");
    DSR(kf1[3], ka1, "6144");
    LGKM0;

    f32x4 stA[4], stB[4];
    __builtin_amdgcn_s_setprio(1);
#pragma unroll
    for (int js = 0; js < 4; ++js) {
      if (aact) {
        stA[js] = mfma32(kf0[js], qfA0, (f32x4){0.f, 0.f, 0.f, 0.f});
        stA[js] = mfma32(kf1[js], qfA1, stA[js]);
      }
      stB[js] = mfma32(kf0[js], qfB0, (f32x4){0.f, 0.f, 0.f, 0.f});
      stB[js] = mfma32(kf1[js], qfB1, stB[js]);
    }
    __builtin_amdgcn_s_setprio(0);

    // V fragments (asm b64) issued now; latency hides under softmax.
    // vf[js][db] at base va{js} + db*2048 bytes
    f16x4 vf[4][4];
    DSR64(vf[0][0], va0, "0");
    DSR64(vf[0][1], va0, "2048");
    DSR64(vf[0][2], va0, "4096");
    DSR64(vf[0][3], va0, "6144");
    DSR64(vf[1][0], va1, "0");
    DSR64(vf[1][1], va1, "2048");
    DSR64(vf[1][2], va1, "4096");
    DSR64(vf[1][3], va1, "6144");
    DSR64(vf[2][0], va2, "0");
    DSR64(vf[2][1], va2, "2048");
    DSR64(vf[2][2], va2, "4096");
    DSR64(vf[2][3], va2, "6144");
    DSR64(vf[3][0], va3, "0");
    DSR64(vf[3][1], va3, "2048");
    DSR64(vf[3][2], va3, "4096");
    DSR64(vf[3][3], va3, "6144");

    f16x4 phA[4], phB[4];
    if (aact)
      softmax16(stA, phA, qA, j0, q0A - j0 >= 192, tab, t128, lg4, mA, lAp,
                oA);
    softmax16(stB, phB, qB, j0, q0B - j0 >= 192, tab, t128, lg4, mB, lBp, oB);

    LGKM0;  // V (and tab) reads retired
    __builtin_amdgcn_s_setprio(1);
#pragma unroll
    for (int js = 0; js < 4; ++js)
#pragma unroll
      for (int db = 0; db < 4; ++db) {
        if (aact) oA[db] = mfma16(phA[js], vf[js][db], oA[db]);
        oB[db] = mfma16(phB[js], vf[js][db], oB[db]);
      }
    __builtin_amdgcn_s_setprio(0);

    __builtin_amdgcn_s_barrier();  // all reads done before restage
    cur ^= 1;
  }

  _Float16* aob = ao + ((size_t)b * 1024) * 1024 + h * 64;
  {
    float lt = lAp + __shfl_xor(lAp, 16);
    lt += __shfl_xor(lt, 32);
    f32x4 linv;
#pragma unroll
    for (int r = 0; r < 4; ++r) linv[r] = 1.0f / __shfl(lt, lg4 + r);
#pragma unroll
    for (int db = 0; db < 4; ++db)
#pragma unroll
      for (int r = 0; r < 4; ++r)
        aob[(size_t)(q0A + lg4 + r) * 1024 + db * 16 + lq] =
            (_Float16)(oA[db][r] * linv[r]);
  }
  {
    float lt = lBp + __shfl_xor(lBp, 16);
    lt += __shfl_xor(lt, 32);
    f32x4 linv;
#pragma unroll
    for (int r = 0; r < 4; ++r) linv[r] = 1.0f / __shfl(lt, lg4 + r);
#pragma unroll
    for (int db = 0; db < 4; ++db)
#pragma unroll
      for (int r = 0; r < 4; ++r)
        aob[(size_t)(q0B + lg4 + r) * 1024 + db * 16 + lq] =
            (_Float16)(oB[db][r] * linv[r]);
  }
}

// -------------------------------- launch ----------------------------------
extern "C" void kernel_launch(void* const* d_in, const int* in_sizes, int n_in,
                              void* d_out, int out_size, void* d_ws,
                              size_t ws_size, hipStream_t stream) {
  const float* x = (const float*)d_in[0];
  const float* qk_w = (const float*)d_in[1];
  const float* qk_b = (const float*)d_in[2];
  const float* v_w = (const float*)d_in[3];
  const float* v_b = (const float*)d_in[4];
  const float* out_w = (const float*)d_in[5];
  const float* out_b = (const float*)d_in[6];
  const float* bias = (const float*)d_in[7];
  float* out = (float*)d_out;

  // workspace (fp16 elems): xb 8M | wb 3M | owb 1M | qk 16M | vt 8M | ao 8M
  _Float16* xb = (_Float16*)d_ws;
  _Float16* wb = xb + (size_t)8388608;
  _Float16* owb = wb + (size_t)3145728;
  _Float16* qkbuf = owb + (size_t)1048576;
  _Float16* vtbuf = qkbuf + (size_t)16777216;
  _Float16* ao = vtbuf + (size_t)8388608;

  // all conversions in one launch
  cvt4_kernel<<<12288, 256, 0, stream>>>(x, qk_w, v_w, out_w, xb, wb,
                                         wb + 2097152, owb);

  // fused QKV projection: M=8192, N=3072 (2048 qk | 1024 v), K=1024
  gemm_kernel<0><<<dim3(24, 64), 256, 0, stream>>>(
      xb, wb, 8192, 3072, 1024, qk_b, v_b, qkbuf, vtbuf, nullptr, nullptr);

  // flash attention: 8 balanced blocks per (b,h)
  attn_kernel<<<1024, 256, 0, stream>>>(qkbuf, vtbuf, bias, ao);

  // output projection: M=8192, N=1024, K=1024 -> fp32 d_out
  gemm_kernel<1><<<dim3(8, 64), 256, 0, stream>>>(
      ao, owb, 8192, 1024, 1024, nullptr, nullptr, nullptr, nullptr, out_b, out);
}

// Round 13
// 179.669 us; speedup vs baseline: 1.2419x; 1.2419x over previous
//
#include <hip/hip_runtime.h>
#include <cmath>

// ---------------------------------------------------------------------------
// T5 MHSA: x->(QKV proj, f16 MFMA GEMM) -> flash attn w/ T5 bias -> out proj
// All matmuls on MFMA. fp16 intermediates, fp32 accum.
// ---------------------------------------------------------------------------

typedef _Float16 f16x8 __attribute__((ext_vector_type(8)));
typedef _Float16 f16x4 __attribute__((ext_vector_type(4)));
typedef float    f32x4 __attribute__((ext_vector_type(4)));

#define NEG_INF (-__builtin_inff())
#define LOG2E 1.4426950408889634f

#if __has_builtin(__builtin_amdgcn_exp2f)
#define EXP2(x) __builtin_amdgcn_exp2f(x)
#else
#define EXP2(x) exp2f(x)
#endif

__device__ __forceinline__ void gl_lds16(const void* g, void* l) {
  __builtin_amdgcn_global_load_lds(
      (__attribute__((address_space(1))) void*)g,
      (__attribute__((address_space(3))) void*)l,
      16, 0, 0);
}

__device__ __forceinline__ f32x4 mfma32(f16x8 a, f16x8 b, f32x4 c) {
  return __builtin_amdgcn_mfma_f32_16x16x32_f16(a, b, c, 0, 0, 0);
}
__device__ __forceinline__ f32x4 mfma16(f16x4 a, f16x4 b, f32x4 c) {
  return __builtin_amdgcn_mfma_f32_16x16x16f16(a, b, c, 0, 0, 0);
}

typedef __attribute__((address_space(3))) _Float16* lds_f16p;

#define DSR(d, a, o) \
  asm volatile("ds_read_b128 %0, %1 offset:" o : "=v"(d) : "v"(a))

// -------------------------------- convert ---------------------------------
// single launch for all 4 fp32->fp16 conversions (saves 3 launch gaps)
__global__ void cvt4_kernel(const float* __restrict__ x,
                            const float* __restrict__ w1,
                            const float* __restrict__ w2,
                            const float* __restrict__ w3,
                            _Float16* __restrict__ ox, _Float16* __restrict__ o1,
                            _Float16* __restrict__ o2, _Float16* __restrict__ o3) {
  const int bid = blockIdx.x;
  const float* src;
  _Float16* dst;
  int idx;
  if (bid < 8192) {
    src = x; dst = ox; idx = bid * 256 + threadIdx.x;
  } else if (bid < 10240) {
    src = w1; dst = o1; idx = (bid - 8192) * 256 + threadIdx.x;
  } else if (bid < 11264) {
    src = w2; dst = o2; idx = (bid - 10240) * 256 + threadIdx.x;
  } else {
    src = w3; dst = o3; idx = (bid - 11264) * 256 + threadIdx.x;
  }
  float4 v = reinterpret_cast<const float4*>(src)[idx];
  f16x4 o;
  o[0] = (_Float16)v.x; o[1] = (_Float16)v.y;
  o[2] = (_Float16)v.z; o[3] = (_Float16)v.w;
  reinterpret_cast<f16x4*>(dst)[idx] = o;
}

// --------------------------------- GEMM -----------------------------------
// C = A(MxK) * Bm(NxK)^T.  128x128 tile, BK=32, 4 waves (2x2 of 64x64).
// 3-deep pipeline (R10 best config, 96.6us): triple-buffer LDS; stage tile
// s+2 during compute of tile s; counted vmcnt(8) keeps 2 tiles in flight
// across raw s_barriers. asm ds_read keeps the loop waitcnt-opaque. LDS
// chunk-XOR swizzle keeps ds_read conflict-free.
#define GEMM_VM8 asm volatile("s_waitcnt vmcnt(8)" ::: "memory")
#define GEMM_VM4 asm volatile("s_waitcnt vmcnt(4)" ::: "memory")
#define GEMM_VM0 asm volatile("s_waitcnt vmcnt(0)" ::: "memory")
#define GEMM_BAR __builtin_amdgcn_s_barrier()

#define GEMM_STAGE(buf, kk)                         \
  do {                                              \
    gl_lds16(pA0 + (kk), &lds_a[buf][wofs]);        \
    gl_lds16(pA1 + (kk), &lds_a[buf][2048 + wofs]); \
    gl_lds16(pB0 + (kk), &lds_b[buf][wofs]);        \
    gl_lds16(pB1 + (kk), &lds_b[buf][2048 + wofs]); \
  } while (0)

#define GEMM_COMPUTE(aB, bB)                             \
  do {                                                   \
    f16x8 af0, af1, af2, af3, bf0, bf1, bf2, bf3;        \
    DSR(af0, aB, "0");                                   \
    DSR(bf0, bB, "0");                                   \
    DSR(af1, aB, "1024");                                \
    DSR(bf1, bB, "1024");                                \
    DSR(af2, aB, "2048");                                \
    DSR(bf2, bB, "2048");                                \
    DSR(af3, aB, "3072");                                \
    DSR(bf3, bB, "3072");                                \
    asm volatile("s_waitcnt lgkmcnt(4)" ::: "memory");   \
    __builtin_amdgcn_sched_barrier(0);                   \
    __builtin_amdgcn_s_setprio(1);                       \
    acc[0][0] = mfma32(af0, bf0, acc[0][0]);             \
    acc[0][1] = mfma32(af0, bf1, acc[0][1]);             \
    acc[1][0] = mfma32(af1, bf0, acc[1][0]);             \
    acc[1][1] = mfma32(af1, bf1, acc[1][1]);             \
    asm volatile("s_waitcnt lgkmcnt(0)" ::: "memory");   \
    __builtin_amdgcn_sched_barrier(0);                   \
    acc[0][2] = mfma32(af0, bf2, acc[0][2]);             \
    acc[0][3] = mfma32(af0, bf3, acc[0][3]);             \
    acc[1][2] = mfma32(af1, bf2, acc[1][2]);             \
    acc[1][3] = mfma32(af1, bf3, acc[1][3]);             \
    acc[2][0] = mfma32(af2, bf0, acc[2][0]);             \
    acc[2][1] = mfma32(af2, bf1, acc[2][1]);             \
    acc[2][2] = mfma32(af2, bf2, acc[2][2]);             \
    acc[2][3] = mfma32(af2, bf3, acc[2][3]);             \
    acc[3][0] = mfma32(af3, bf0, acc[3][0]);             \
    acc[3][1] = mfma32(af3, bf1, acc[3][1]);             \
    acc[3][2] = mfma32(af3, bf2, acc[3][2]);             \
    acc[3][3] = mfma32(af3, bf3, acc[3][3]);             \
    __builtin_amdgcn_s_setprio(0);                       \
  } while (0)

template <int MODE>
__global__ __launch_bounds__(256, 3) void gemm_kernel(
    const _Float16* __restrict__ A, const _Float16* __restrict__ Bm,
    int M, int N, int K,
    const float* __restrict__ bias_q, const float* __restrict__ bias_v,
    _Float16* __restrict__ qkbuf, _Float16* __restrict__ vtbuf,
    const float* __restrict__ bias_o, float* __restrict__ outf) {
  __shared__ __align__(16) _Float16 lds_a[3][128 * 32];
  __shared__ __align__(16) _Float16 lds_b[3][128 * 32];
  const int t = threadIdx.x;
  const int w = t >> 6;
  const int lane = t & 63;
  const int lq = lane & 15, lg = lane >> 4;
  const int wr = w >> 1, wc = w & 1;
  const int m0 = blockIdx.y * 128, n0 = blockIdx.x * 128;

  const int stc = ((t & 3) ^ ((t >> 3) & 3)) * 8;
  const _Float16* pA0 = A + (size_t)(m0 + (t >> 2)) * K + stc;
  const _Float16* pA1 = pA0 + (size_t)64 * K;
  const _Float16* pB0 = Bm + (size_t)(n0 + (t >> 2)) * K + stc;
  const _Float16* pB1 = pB0 + (size_t)64 * K;
  const int wofs = w * 512;

  const int xsw = (lq >> 1) & 3;
  const uint32_t aB0 = (uint32_t)(uintptr_t)(lds_f16p)&lds_a[0][0] +
                       (uint32_t)((wr * 64 + lq) * 64 + ((lg ^ xsw) << 4));
  const uint32_t aB1 = aB0 + 8192;
  const uint32_t aB2 = aB0 + 16384;
  const uint32_t bB0 = (uint32_t)(uintptr_t)(lds_f16p)&lds_b[0][0] +
                       (uint32_t)((wc * 64 + lq) * 64 + ((lg ^ xsw) << 4));
  const uint32_t bB1 = bB0 + 8192;
  const uint32_t bB2 = bB0 + 16384;

  f32x4 acc[4][4];
#pragma unroll
  for (int mi = 0; mi < 4; ++mi)
#pragma unroll
    for (int ni = 0; ni < 4; ++ni) acc[mi][ni] = (f32x4){0.f, 0.f, 0.f, 0.f};

  GEMM_STAGE(0, 0);
  GEMM_STAGE(1, 32);
  for (int kt = 0; kt + 160 <= K; kt += 96) {
    GEMM_STAGE(2, kt + 64);
    GEMM_VM8;
    GEMM_BAR;
    GEMM_COMPUTE(aB0, bB0);
    GEMM_BAR;
    GEMM_STAGE(0, kt + 96);
    GEMM_VM8;
    GEMM_BAR;
    GEMM_COMPUTE(aB1, bB1);
    GEMM_BAR;
    GEMM_STAGE(1, kt + 128);
    GEMM_VM8;
    GEMM_BAR;
    GEMM_COMPUTE(aB2, bB2);
    GEMM_BAR;
  }
  GEMM_VM4;
  GEMM_BAR;
  GEMM_COMPUTE(aB0, bB0);
  GEMM_BAR;
  GEMM_VM0;
  GEMM_BAR;
  GEMM_COMPUTE(aB1, bB1);

  if (MODE == 0) {
    const bool isqk = (n0 < 2048);
#pragma unroll
    for (int mi = 0; mi < 4; ++mi)
#pragma unroll
      for (int ni = 0; ni < 4; ++ni)
#pragma unroll
        for (int r = 0; r < 4; ++r) {
          const int mg = m0 + wr * 64 + mi * 16 + lg * 4 + r;
          const int ng = n0 + wc * 64 + ni * 16 + lq;
          const int bb = mg >> 10, ii = mg & 1023;
          float val = acc[mi][ni][r];
          if (isqk) {
            val += bias_q[ng];
            const int hh = ng >> 7, cc = ng & 127;
            qkbuf[((size_t)((bb * 16 + hh) * 1024 + ii)) * 128 + cc] =
                (_Float16)val;
          } else {
            const int nn = ng - 2048;
            val += bias_v[nn];
            const int hh = nn >> 6, dv = nn & 63;
            vtbuf[((size_t)((bb * 16 + hh) * 64 + dv)) * 1024 + ii] =
                (_Float16)val;
          }
        }
  } else {
#pragma unroll
    for (int mi = 0; mi < 4; ++mi)
#pragma unroll
      for (int ni = 0; ni < 4; ++ni)
#pragma unroll
        for (int r = 0; r < 4; ++r) {
          const int mg = m0 + wr * 64 + mi * 16 + lg * 4 + r;
          const int ng = n0 + wc * 64 + ni * 16 + lq;
          outf[(size_t)mg * N + ng] = acc[mi][ni][r] + bias_o[ng];
        }
  }
}

// ------------------------------- attention --------------------------------
// R11 known-good version (typed LDS reads, single __syncthreads, compiler
// scheduling — the asm/order-pinned variant regressed 2x, m141-style).
// Block = 4 waves, owns q-tile PAIR (tA=b4, tB=15-b4) of one (b,h): constant
// work per block, all waves share the same j-range -> barrier-synced LDS
// staging of K/V tiles (KVBLK=64), double-buffered, swizzled.
__device__ __forceinline__ void stage_kv(const _Float16* __restrict__ kb,
                                         const _Float16* __restrict__ vtb,
                                         int j0, _Float16* kl, _Float16* vl,
                                         int t) {
  const int r0 = t >> 3, c0 = t & 7;
  const int r1 = r0 + 32;
  const int kc0 = c0 ^ (r0 & 7), kc1 = c0 ^ (r1 & 7);
  gl_lds16(kb + (size_t)(j0 + r0) * 128 + kc0 * 8, kl + t * 8);
  gl_lds16(kb + (size_t)(j0 + r1) * 128 + kc1 * 8, kl + (t + 256) * 8);
  gl_lds16(vtb + (size_t)r0 * 1024 + j0 + kc0 * 8, vl + t * 8);
  gl_lds16(vtb + (size_t)r1 * 1024 + j0 + kc1 * 8, vl + (t + 256) * 8);
}

__device__ __forceinline__ void softmax16(f32x4 (&st)[4], f16x4 (&ph)[4],
                                          int qi, int j0, bool far,
                                          const float* __restrict__ tab,
                                          float t128, int lg4, float& m_run,
                                          float& l_part, f32x4 (&oacc)[4]) {
  float xs[16];
  float lmax = NEG_INF;
  if (far) {
#pragma unroll
    for (int js = 0; js < 4; ++js)
#pragma unroll
      for (int r = 0; r < 4; ++r) {
        const float xv = fmaf(st[js][r], 0.125f * LOG2E, t128);
        xs[js * 4 + r] = xv;
        lmax = fmaxf(lmax, xv);
      }
  } else {
#pragma unroll
    for (int js = 0; js < 4; ++js)
#pragma unroll
      for (int r = 0; r < 4; ++r) {
        const int jj = j0 + js * 16 + lg4 + r;
        const int dd = qi - jj;
        const int idx = dd < 0 ? 0 : (dd > 128 ? 128 : dd);
        const float xv =
            (dd < 0) ? NEG_INF : fmaf(st[js][r], 0.125f * LOG2E, tab[idx]);
        xs[js * 4 + r] = xv;
        lmax = fmaxf(lmax, xv);
      }
  }
  if (__any(lmax > m_run + 8.0f)) {
    float tmax = fmaxf(lmax, __shfl_xor(lmax, 16));
    tmax = fmaxf(tmax, __shfl_xor(tmax, 32));
    const float m_new = fmaxf(m_run, tmax);
    const float sf = EXP2(m_run - m_new);
    m_run = m_new;
    l_part *= sf;
    f32x4 sfv;
#pragma unroll
    for (int r = 0; r < 4; ++r) sfv[r] = __shfl(sf, lg4 + r);
#pragma unroll
    for (int db = 0; db < 4; ++db) oacc[db] *= sfv;
  }
  float ls = 0.f;
#pragma unroll
  for (int js = 0; js < 4; ++js)
#pragma unroll
    for (int r = 0; r < 4; ++r) {
      const float p = EXP2(xs[js * 4 + r] - m_run);
      ls += p;
      ph[js][r] = (_Float16)p;
    }
  l_part += ls;
}

__global__ __launch_bounds__(256, 4) void attn_kernel(
    const _Float16* __restrict__ qk,  // [B*H][1024][128] (q | k)
    const _Float16* __restrict__ vt,  // [B*H][64][1024]  (V^T)
    const float* __restrict__ bias,   // [32][16]
    _Float16* __restrict__ ao) {      // [B][1024][H*64]
  __shared__ __align__(16) _Float16 kls[2][64 * 64];
  __shared__ __align__(16) _Float16 vls[2][64 * 64];
  __shared__ float tab[132];
  const int t = threadIdx.x;
  const int bid = blockIdx.x;
  const int bh = (bid & 7) * 16 + (bid >> 6);
  const int b4 = (bid >> 3) & 7;
  const int h = bh & 15, b = bh >> 4;
  if (t < 129) {
    const int bucket =
        (t <= 16) ? t : 16 + (int)(log((double)(t - 15)) * 15.0 / log(113.0));
    tab[t] = bias[bucket * 16 + h] * LOG2E;
  }

  const int w = t >> 6, lane = t & 63;
  const int lq = lane & 15, lg = lane >> 4;
  const int lg4 = lg * 4, lg8 = lg * 8;
  const int tA = b4, tB = 15 - b4;
  const int q0A = tA * 64 + w * 16, q0B = tB * 64 + w * 16;
  const int qA = q0A + lq, qB = q0B + lq;
  const _Float16* qkb = qk + (size_t)bh * 1024 * 128;
  const _Float16* kb = qkb + 64;
  const _Float16* vtb = vt + (size_t)bh * 64 * 1024;

  const f16x8 qfA0 = *(const f16x8*)&qkb[qA * 128 + lg8];
  const f16x8 qfA1 = *(const f16x8*)&qkb[qA * 128 + 32 + lg8];
  const f16x8 qfB0 = *(const f16x8*)&qkb[qB * 128 + lg8];
  const f16x8 qfB1 = *(const f16x8*)&qkb[qB * 128 + 32 + lg8];

  f32x4 oA[4], oB[4];
#pragma unroll
  for (int db = 0; db < 4; ++db) {
    oA[db] = (f32x4){0.f, 0.f, 0.f, 0.f};
    oB[db] = (f32x4){0.f, 0.f, 0.f, 0.f};
  }
  float mA = NEG_INF, lAp = 0.f, mB = NEG_INF, lBp = 0.f;

  stage_kv(kb, vtb, 0, kls[0], vls[0], t);
  __syncthreads();
  const float t128 = tab[128];
  const int krsw = lq & 7;
  const int vsw = (lq & 7) << 1;
  int cur = 0;

  for (int jt = 0; jt <= tB; ++jt) {
    const int j0 = jt * 64;
    if (jt < tB) stage_kv(kb, vtb, j0 + 64, kls[cur ^ 1], vls[cur ^ 1], t);
    const bool aact = (jt <= tA);
    const _Float16* kbf = kls[cur];
    const _Float16* vbf = vls[cur];

    f32x4 stA[4], stB[4];
#pragma unroll
    for (int js = 0; js < 4; ++js) {
      const int rowb = (js * 16 + lq) * 64;
      const f16x8 kf0 = *(const f16x8*)&kbf[rowb + ((lg ^ krsw) << 3)];
      const f16x8 kf1 = *(const f16x8*)&kbf[rowb + (((lg + 4) ^ krsw) << 3)];
      if (aact) {
        stA[js] = mfma32(kf0, qfA0, (f32x4){0.f, 0.f, 0.f, 0.f});
        stA[js] = mfma32(kf1, qfA1, stA[js]);
      }
      stB[js] = mfma32(kf0, qfB0, (f32x4){0.f, 0.f, 0.f, 0.f});
      stB[js] = mfma32(kf1, qfB1, stB[js]);
    }

    f16x4 phA[4], phB[4];
    if (aact)
      softmax16(stA, phA, qA, j0, q0A - j0 >= 192, tab, t128, lg4, mA, lAp,
                oA);
    softmax16(stB, phB, qB, j0, q0B - j0 >= 192, tab, t128, lg4, mB, lBp, oB);

#pragma unroll
    for (int js = 0; js < 4; ++js)
#pragma unroll
      for (int db = 0; db < 4; ++db) {
        const f16x4 vf = *(const f16x4*)&vbf[(db * 16 + lq) * 64 +
                                             ((((js << 2) + lg) ^ vsw) << 2)];
        if (aact) oA[db] = mfma16(phA[js], vf, oA[db]);
        oB[db] = mfma16(phB[js], vf, oB[db]);
      }

    __syncthreads();
    cur ^= 1;
  }

  _Float16* aob = ao + ((size_t)b * 1024) * 1024 + h * 64;
  {
    float lt = lAp + __shfl_xor(lAp, 16);
    lt += __shfl_xor(lt, 32);
    f32x4 linv;
#pragma unroll
    for (int r = 0; r < 4; ++r) linv[r] = 1.0f / __shfl(lt, lg4 + r);
#pragma unroll
    for (int db = 0; db < 4; ++db)
#pragma unroll
      for (int r = 0; r < 4; ++r)
        aob[(size_t)(q0A + lg4 + r) * 1024 + db * 16 + lq] =
            (_Float16)(oA[db][r] * linv[r]);
  }
  {
    float lt = lBp + __shfl_xor(lBp, 16);
    lt += __shfl_xor(lt, 32);
    f32x4 linv;
#pragma unroll
    for (int r = 0; r < 4; ++r) linv[r] = 1.0f / __shfl(lt, lg4 + r);
#pragma unroll
    for (int db = 0; db < 4; ++db)
#pragma unroll
      for (int r = 0; r < 4; ++r)
        aob[(size_t)(q0B + lg4 + r) * 1024 + db * 16 + lq] =
            (_Float16)(oB[db][r] * linv[r]);
  }
}

// -------------------------------- launch ----------------------------------
extern "C" void kernel_launch(void* const* d_in, const int* in_sizes, int n_in,
                              void* d_out, int out_size, void* d_ws,
                              size_t ws_size, hipStream_t stream) {
  const float* x = (const float*)d_in[0];
  const float* qk_w = (const float*)d_in[1];
  const float* qk_b = (const float*)d_in[2];
  const float* v_w = (const float*)d_in[3];
  const float* v_b = (const float*)d_in[4];
  const float* out_w = (const float*)d_in[5];
  const float* out_b = (const float*)d_in[6];
  const float* bias = (const float*)d_in[7];
  float* out = (float*)d_out;

  // workspace (fp16 elems): xb 8M | wb 3M | owb 1M | qk 16M | vt 8M | ao 8M
  _Float16* xb = (_Float16*)d_ws;
  _Float16* wb = xb + (size_t)8388608;
  _Float16* owb = wb + (size_t)3145728;
  _Float16* qkbuf = owb + (size_t)1048576;
  _Float16* vtbuf = qkbuf + (size_t)16777216;
  _Float16* ao = vtbuf + (size_t)8388608;

  // all conversions in one launch
  cvt4_kernel<<<12288, 256, 0, stream>>>(x, qk_w, v_w, out_w, xb, wb,
                                         wb + 2097152, owb);

  // fused QKV projection: M=8192, N=3072 (2048 qk | 1024 v), K=1024
  gemm_kernel<0><<<dim3(24, 64), 256, 0, stream>>>(
      xb, wb, 8192, 3072, 1024, qk_b, v_b, qkbuf, vtbuf, nullptr, nullptr);

  // flash attention: 8 balanced blocks per (b,h)
  attn_kernel<<<1024, 256, 0, stream>>>(qkbuf, vtbuf, bias, ao);

  // output projection: M=8192, N=1024, K=1024 -> fp32 d_out
  gemm_kernel<1><<<dim3(8, 64), 256, 0, stream>>>(
      ao, owb, 8192, 1024, 1024, nullptr, nullptr, nullptr, nullptr, out_b, out);
}

// Round 14
// 157.403 us; speedup vs baseline: 1.4176x; 1.1415x over previous
//
#include <hip/hip_runtime.h>
#include <cmath>

// ---------------------------------------------------------------------------
// T5 MHSA: x->(QKV proj, f16 MFMA GEMM) -> flash attn w/ T5 bias -> out proj
// All matmuls on MFMA. fp16 intermediates, fp32 accum.
// ---------------------------------------------------------------------------

typedef _Float16 f16x8 __attribute__((ext_vector_type(8)));
typedef _Float16 f16x4 __attribute__((ext_vector_type(4)));
typedef float    f32x4 __attribute__((ext_vector_type(4)));

#define NEG_INF (-__builtin_inff())
#define LOG2E 1.4426950408889634f

#if __has_builtin(__builtin_amdgcn_exp2f)
#define EXP2(x) __builtin_amdgcn_exp2f(x)
#else
#define EXP2(x) exp2f(x)
#endif

__device__ __forceinline__ void gl_lds16(const void* g, void* l) {
  __builtin_amdgcn_global_load_lds(
      (__attribute__((address_space(1))) void*)g,
      (__attribute__((address_space(3))) void*)l,
      16, 0, 0);
}

__device__ __forceinline__ f32x4 mfma32(f16x8 a, f16x8 b, f32x4 c) {
  return __builtin_amdgcn_mfma_f32_16x16x32_f16(a, b, c, 0, 0, 0);
}
__device__ __forceinline__ f32x4 mfma16(f16x4 a, f16x4 b, f32x4 c) {
  return __builtin_amdgcn_mfma_f32_16x16x16f16(a, b, c, 0, 0, 0);
}

typedef __attribute__((address_space(3))) _Float16* lds_f16p;

#define DSR(d, a, o) \
  asm volatile("ds_read_b128 %0, %1 offset:" o : "=v"(d) : "v"(a))

// -------------------------------- convert ---------------------------------
// single launch for all 4 fp32->fp16 conversions (saves 3 launch gaps)
__global__ void cvt4_kernel(const float* __restrict__ x,
                            const float* __restrict__ w1,
                            const float* __restrict__ w2,
                            const float* __restrict__ w3,
                            _Float16* __restrict__ ox, _Float16* __restrict__ o1,
                            _Float16* __restrict__ o2, _Float16* __restrict__ o3) {
  const int bid = blockIdx.x;
  const float* src;
  _Float16* dst;
  int idx;
  if (bid < 8192) {
    src = x; dst = ox; idx = bid * 256 + threadIdx.x;
  } else if (bid < 10240) {
    src = w1; dst = o1; idx = (bid - 8192) * 256 + threadIdx.x;
  } else if (bid < 11264) {
    src = w2; dst = o2; idx = (bid - 10240) * 256 + threadIdx.x;
  } else {
    src = w3; dst = o3; idx = (bid - 11264) * 256 + threadIdx.x;
  }
  float4 v = reinterpret_cast<const float4*>(src)[idx];
  f16x4 o;
  o[0] = (_Float16)v.x; o[1] = (_Float16)v.y;
  o[2] = (_Float16)v.z; o[3] = (_Float16)v.w;
  reinterpret_cast<f16x4*>(dst)[idx] = o;
}

// --------------------------------- GEMM -----------------------------------
// C = A(MxK) * Bm(NxK)^T.  128x128 tile, BK=32, 4 waves (2x2 of 64x64).
// 3-deep pipeline (R10/R13 best config): triple-buffer LDS; stage tile s+2
// during compute of tile s; counted vmcnt(8) keeps 2 tiles in flight across
// raw s_barriers. asm ds_read keeps the loop waitcnt-opaque. LDS chunk-XOR
// swizzle keeps ds_read conflict-free.
// NEW (R14): MODE-0 epilogue stages the C-tile through LDS (freed after the
// K-loop) so qk/v outputs are written with fully-coalesced wave-wide f16x8
// stores instead of 64 scattered scalar fp16 stores per thread.
#define GEMM_VM8 asm volatile("s_waitcnt vmcnt(8)" ::: "memory")
#define GEMM_VM4 asm volatile("s_waitcnt vmcnt(4)" ::: "memory")
#define GEMM_VM0 asm volatile("s_waitcnt vmcnt(0)" ::: "memory")
#define GEMM_BAR __builtin_amdgcn_s_barrier()

// lds layout (f16 elems): A bufs [0,12288) = 3 x 4096, B bufs [12288,24576)
#define GEMM_STAGE(buf, kk)                                        \
  do {                                                             \
    gl_lds16(pA0 + (kk), &lds[(buf)*4096 + wofs]);                 \
    gl_lds16(pA1 + (kk), &lds[(buf)*4096 + 2048 + wofs]);          \
    gl_lds16(pB0 + (kk), &lds[12288 + (buf)*4096 + wofs]);         \
    gl_lds16(pB1 + (kk), &lds[12288 + (buf)*4096 + 2048 + wofs]);  \
  } while (0)

#define GEMM_COMPUTE(aB, bB)                             \
  do {                                                   \
    f16x8 af0, af1, af2, af3, bf0, bf1, bf2, bf3;        \
    DSR(af0, aB, "0");                                   \
    DSR(bf0, bB, "0");                                   \
    DSR(af1, aB, "1024");                                \
    DSR(bf1, bB, "1024");                                \
    DSR(af2, aB, "2048");                                \
    DSR(bf2, bB, "2048");                                \
    DSR(af3, aB, "3072");                                \
    DSR(bf3, bB, "3072");                                \
    asm volatile("s_waitcnt lgkmcnt(4)" ::: "memory");   \
    __builtin_amdgcn_sched_barrier(0);                   \
    __builtin_amdgcn_s_setprio(1);                       \
    acc[0][0] = mfma32(af0, bf0, acc[0][0]);             \
    acc[0][1] = mfma32(af0, bf1, acc[0][1]);             \
    acc[1][0] = mfma32(af1, bf0, acc[1][0]);             \
    acc[1][1] = mfma32(af1, bf1, acc[1][1]);             \
    asm volatile("s_waitcnt lgkmcnt(0)" ::: "memory");   \
    __builtin_amdgcn_sched_barrier(0);                   \
    acc[0][2] = mfma32(af0, bf2, acc[0][2]);             \
    acc[0][3] = mfma32(af0, bf3, acc[0][3]);             \
    acc[1][2] = mfma32(af1, bf2, acc[1][2]);             \
    acc[1][3] = mfma32(af1, bf3, acc[1][3]);             \
    acc[2][0] = mfma32(af2, bf0, acc[2][0]);             \
    acc[2][1] = mfma32(af2, bf1, acc[2][1]);             \
    acc[2][2] = mfma32(af2, bf2, acc[2][2]);             \
    acc[2][3] = mfma32(af2, bf3, acc[2][3]);             \
    acc[3][0] = mfma32(af3, bf0, acc[3][0]);             \
    acc[3][1] = mfma32(af3, bf1, acc[3][1]);             \
    acc[3][2] = mfma32(af3, bf2, acc[3][2]);             \
    acc[3][3] = mfma32(af3, bf3, acc[3][3]);             \
    __builtin_amdgcn_s_setprio(0);                       \
  } while (0)

template <int MODE>
__global__ __launch_bounds__(256, 3) void gemm_kernel(
    const _Float16* __restrict__ A, const _Float16* __restrict__ Bm,
    int M, int N, int K,
    const float* __restrict__ bias_q, const float* __restrict__ bias_v,
    _Float16* __restrict__ qkbuf, _Float16* __restrict__ vtbuf,
    const float* __restrict__ bias_o, float* __restrict__ outf) {
  __shared__ __align__(16) _Float16 lds[6 * 4096];  // 48 KB, reused by epilogue
  const int t = threadIdx.x;
  const int w = t >> 6;
  const int lane = t & 63;
  const int lq = lane & 15, lg = lane >> 4;
  const int wr = w >> 1, wc = w & 1;
  const int m0 = blockIdx.y * 128, n0 = blockIdx.x * 128;

  const int stc = ((t & 3) ^ ((t >> 3) & 3)) * 8;
  const _Float16* pA0 = A + (size_t)(m0 + (t >> 2)) * K + stc;
  const _Float16* pA1 = pA0 + (size_t)64 * K;
  const _Float16* pB0 = Bm + (size_t)(n0 + (t >> 2)) * K + stc;
  const _Float16* pB1 = pB0 + (size_t)64 * K;
  const int wofs = w * 512;

  const int xsw = (lq >> 1) & 3;
  const uint32_t base = (uint32_t)(uintptr_t)(lds_f16p)&lds[0];
  const uint32_t aB0 =
      base + (uint32_t)((wr * 64 + lq) * 64 + ((lg ^ xsw) << 4));
  const uint32_t aB1 = aB0 + 8192;
  const uint32_t aB2 = aB0 + 16384;
  const uint32_t bB0 =
      base + 24576 + (uint32_t)((wc * 64 + lq) * 64 + ((lg ^ xsw) << 4));
  const uint32_t bB1 = bB0 + 8192;
  const uint32_t bB2 = bB0 + 16384;

  f32x4 acc[4][4];
#pragma unroll
  for (int mi = 0; mi < 4; ++mi)
#pragma unroll
    for (int ni = 0; ni < 4; ++ni) acc[mi][ni] = (f32x4){0.f, 0.f, 0.f, 0.f};

  GEMM_STAGE(0, 0);
  GEMM_STAGE(1, 32);
  for (int kt = 0; kt + 160 <= K; kt += 96) {
    GEMM_STAGE(2, kt + 64);
    GEMM_VM8;
    GEMM_BAR;
    GEMM_COMPUTE(aB0, bB0);
    GEMM_BAR;
    GEMM_STAGE(0, kt + 96);
    GEMM_VM8;
    GEMM_BAR;
    GEMM_COMPUTE(aB1, bB1);
    GEMM_BAR;
    GEMM_STAGE(1, kt + 128);
    GEMM_VM8;
    GEMM_BAR;
    GEMM_COMPUTE(aB2, bB2);
    GEMM_BAR;
  }
  GEMM_VM4;
  GEMM_BAR;
  GEMM_COMPUTE(aB0, bB0);
  GEMM_BAR;
  GEMM_VM0;
  GEMM_BAR;
  GEMM_COMPUTE(aB1, bB1);

  if (MODE == 0) {
    // coalesced epilogue via LDS staging tile T[128][136] (f16, 34.8 KB)
    GEMM_BAR;  // all waves done reading frag buffers; lds reusable
    _Float16* T = &lds[0];
    const bool isqk = (n0 < 2048);  // block-uniform
    const int bb = m0 >> 10, ii0 = m0 & 1023;
    if (isqk) {
      // T[row][col] = C + bias_q; out rows are contiguous 256B panels
#pragma unroll
      for (int mi = 0; mi < 4; ++mi)
#pragma unroll
        for (int ni = 0; ni < 4; ++ni) {
          const int col = wc * 64 + ni * 16 + lq;
          const float bq = bias_q[n0 + col];
#pragma unroll
          for (int r = 0; r < 4; ++r) {
            const int row = wr * 64 + mi * 16 + lg * 4 + r;
            T[row * 136 + col] = (_Float16)(acc[mi][ni][r] + bq);
          }
        }
      __syncthreads();
      const int hh = n0 >> 7;  // one head per 128-wide tile
      _Float16* gb = qkbuf + ((size_t)((bb * 16 + hh) * 1024 + ii0)) * 128;
      const int row = t >> 1, half = t & 1;
      const int so = row * 136 + half * 64;
      const int go = row * 128 + half * 64;
#pragma unroll
      for (int j = 0; j < 8; ++j)
        *(f16x8*)(gb + go + j * 8) = *(const f16x8*)&T[so + j * 8];
    } else {
      // T[col][row] = C^T + bias_v (f16x4-packed); out rows = vtbuf segments
      const int nn0 = n0 - 2048;
#pragma unroll
      for (int mi = 0; mi < 4; ++mi)
#pragma unroll
        for (int ni = 0; ni < 4; ++ni) {
          const int col = wc * 64 + ni * 16 + lq;
          const float bv = bias_v[nn0 + col];
          const int row0 = wr * 64 + mi * 16 + lg * 4;
          f16x4 p;
#pragma unroll
          for (int r = 0; r < 4; ++r) p[r] = (_Float16)(acc[mi][ni][r] + bv);
          *(f16x4*)&T[col * 136 + row0] = p;
        }
      __syncthreads();
      const int c = t >> 1, half = t & 1;
      const int nn = nn0 + c;
      const int hh = nn >> 6, dv = nn & 63;
      _Float16* gb = vtbuf + ((size_t)((bb * 16 + hh) * 64 + dv)) * 1024 +
                     ii0 + half * 64;
      const int so = c * 136 + half * 64;
#pragma unroll
      for (int j = 0; j < 8; ++j)
        *(f16x8*)(gb + j * 8) = *(const f16x8*)&T[so + j * 8];
    }
  } else {
#pragma unroll
    for (int mi = 0; mi < 4; ++mi)
#pragma unroll
      for (int ni = 0; ni < 4; ++ni)
#pragma unroll
        for (int r = 0; r < 4; ++r) {
          const int mg = m0 + wr * 64 + mi * 16 + lg * 4 + r;
          const int ng = n0 + wc * 64 + ni * 16 + lq;
          outf[(size_t)mg * N + ng] = acc[mi][ni][r] + bias_o[ng];
        }
  }
}

// ------------------------------- attention --------------------------------
// R11/R13 known-good version (typed LDS reads, single __syncthreads,
// compiler scheduling). Block = 4 waves, owns q-tile PAIR (tA=b4, tB=15-b4)
// of one (b,h): constant work per block; barrier-synced LDS staging of K/V
// tiles (KVBLK=64), double-buffered, swizzled.
__device__ __forceinline__ void stage_kv(const _Float16* __restrict__ kb,
                                         const _Float16* __restrict__ vtb,
                                         int j0, _Float16* kl, _Float16* vl,
                                         int t) {
  const int r0 = t >> 3, c0 = t & 7;
  const int r1 = r0 + 32;
  const int kc0 = c0 ^ (r0 & 7), kc1 = c0 ^ (r1 & 7);
  gl_lds16(kb + (size_t)(j0 + r0) * 128 + kc0 * 8, kl + t * 8);
  gl_lds16(kb + (size_t)(j0 + r1) * 128 + kc1 * 8, kl + (t + 256) * 8);
  gl_lds16(vtb + (size_t)r0 * 1024 + j0 + kc0 * 8, vl + t * 8);
  gl_lds16(vtb + (size_t)r1 * 1024 + j0 + kc1 * 8, vl + (t + 256) * 8);
}

__device__ __forceinline__ void softmax16(f32x4 (&st)[4], f16x4 (&ph)[4],
                                          int qi, int j0, bool far,
                                          const float* __restrict__ tab,
                                          float t128, int lg4, float& m_run,
                                          float& l_part, f32x4 (&oacc)[4]) {
  float xs[16];
  float lmax = NEG_INF;
  if (far) {
#pragma unroll
    for (int js = 0; js < 4; ++js)
#pragma unroll
      for (int r = 0; r < 4; ++r) {
        const float xv = fmaf(st[js][r], 0.125f * LOG2E, t128);
        xs[js * 4 + r] = xv;
        lmax = fmaxf(lmax, xv);
      }
  } else {
#pragma unroll
    for (int js = 0; js < 4; ++js)
#pragma unroll
      for (int r = 0; r < 4; ++r) {
        const int jj = j0 + js * 16 + lg4 + r;
        const int dd = qi - jj;
        const int idx = dd < 0 ? 0 : (dd > 128 ? 128 : dd);
        const float xv =
            (dd < 0) ? NEG_INF : fmaf(st[js][r], 0.125f * LOG2E, tab[idx]);
        xs[js * 4 + r] = xv;
        lmax = fmaxf(lmax, xv);
      }
  }
  if (__any(lmax > m_run + 8.0f)) {
    float tmax = fmaxf(lmax, __shfl_xor(lmax, 16));
    tmax = fmaxf(tmax, __shfl_xor(tmax, 32));
    const float m_new = fmaxf(m_run, tmax);
    const float sf = EXP2(m_run - m_new);
    m_run = m_new;
    l_part *= sf;
    f32x4 sfv;
#pragma unroll
    for (int r = 0; r < 4; ++r) sfv[r] = __shfl(sf, lg4 + r);
#pragma unroll
    for (int db = 0; db < 4; ++db) oacc[db] *= sfv;
  }
  float ls = 0.f;
#pragma unroll
  for (int js = 0; js < 4; ++js)
#pragma unroll
    for (int r = 0; r < 4; ++r) {
      const float p = EXP2(xs[js * 4 + r] - m_run);
      ls += p;
      ph[js][r] = (_Float16)p;
    }
  l_part += ls;
}

__global__ __launch_bounds__(256, 4) void attn_kernel(
    const _Float16* __restrict__ qk,  // [B*H][1024][128] (q | k)
    const _Float16* __restrict__ vt,  // [B*H][64][1024]  (V^T)
    const float* __restrict__ bias,   // [32][16]
    _Float16* __restrict__ ao) {      // [B][1024][H*64]
  __shared__ __align__(16) _Float16 kls[2][64 * 64];
  __shared__ __align__(16) _Float16 vls[2][64 * 64];
  __shared__ float tab[132];
  const int t = threadIdx.x;
  const int bid = blockIdx.x;
  const int bh = (bid & 7) * 16 + (bid >> 6);
  const int b4 = (bid >> 3) & 7;
  const int h = bh & 15, b = bh >> 4;
  if (t < 129) {
    const int bucket =
        (t <= 16) ? t : 16 + (int)(log((double)(t - 15)) * 15.0 / log(113.0));
    tab[t] = bias[bucket * 16 + h] * LOG2E;
  }

  const int w = t >> 6, lane = t & 63;
  const int lq = lane & 15, lg = lane >> 4;
  const int lg4 = lg * 4, lg8 = lg * 8;
  const int tA = b4, tB = 15 - b4;
  const int q0A = tA * 64 + w * 16, q0B = tB * 64 + w * 16;
  const int qA = q0A + lq, qB = q0B + lq;
  const _Float16* qkb = qk + (size_t)bh * 1024 * 128;
  const _Float16* kb = qkb + 64;
  const _Float16* vtb = vt + (size_t)bh * 64 * 1024;

  const f16x8 qfA0 = *(const f16x8*)&qkb[qA * 128 + lg8];
  const f16x8 qfA1 = *(const f16x8*)&qkb[qA * 128 + 32 + lg8];
  const f16x8 qfB0 = *(const f16x8*)&qkb[qB * 128 + lg8];
  const f16x8 qfB1 = *(const f16x8*)&qkb[qB * 128 + 32 + lg8];

  f32x4 oA[4], oB[4];
#pragma unroll
  for (int db = 0; db < 4; ++db) {
    oA[db] = (f32x4){0.f, 0.f, 0.f, 0.f};
    oB[db] = (f32x4){0.f, 0.f, 0.f, 0.f};
  }
  float mA = NEG_INF, lAp = 0.f, mB = NEG_INF, lBp = 0.f;

  stage_kv(kb, vtb, 0, kls[0], vls[0], t);
  __syncthreads();
  const float t128 = tab[128];
  const int krsw = lq & 7;
  const int vsw = (lq & 7) << 1;
  int cur = 0;

  for (int jt = 0; jt <= tB; ++jt) {
    const int j0 = jt * 64;
    if (jt < tB) stage_kv(kb, vtb, j0 + 64, kls[cur ^ 1], vls[cur ^ 1], t);
    const bool aact = (jt <= tA);
    const _Float16* kbf = kls[cur];
    const _Float16* vbf = vls[cur];

    f32x4 stA[4], stB[4];
#pragma unroll
    for (int js = 0; js < 4; ++js) {
      const int rowb = (js * 16 + lq) * 64;
      const f16x8 kf0 = *(const f16x8*)&kbf[rowb + ((lg ^ krsw) << 3)];
      const f16x8 kf1 = *(const f16x8*)&kbf[rowb + (((lg + 4) ^ krsw) << 3)];
      if (aact) {
        stA[js] = mfma32(kf0, qfA0, (f32x4){0.f, 0.f, 0.f, 0.f});
        stA[js] = mfma32(kf1, qfA1, stA[js]);
      }
      stB[js] = mfma32(kf0, qfB0, (f32x4){0.f, 0.f, 0.f, 0.f});
      stB[js] = mfma32(kf1, qfB1, stB[js]);
    }

    f16x4 phA[4], phB[4];
    if (aact)
      softmax16(stA, phA, qA, j0, q0A - j0 >= 192, tab, t128, lg4, mA, lAp,
                oA);
    softmax16(stB, phB, qB, j0, q0B - j0 >= 192, tab, t128, lg4, mB, lBp, oB);

#pragma unroll
    for (int js = 0; js < 4; ++js)
#pragma unroll
      for (int db = 0; db < 4; ++db) {
        const f16x4 vf = *(const f16x4*)&vbf[(db * 16 + lq) * 64 +
                                             ((((js << 2) + lg) ^ vsw) << 2)];
        if (aact) oA[db] = mfma16(phA[js], vf, oA[db]);
        oB[db] = mfma16(phB[js], vf, oB[db]);
      }

    __syncthreads();
    cur ^= 1;
  }

  _Float16* aob = ao + ((size_t)b * 1024) * 1024 + h * 64;
  {
    float lt = lAp + __shfl_xor(lAp, 16);
    lt += __shfl_xor(lt, 32);
    f32x4 linv;
#pragma unroll
    for (int r = 0; r < 4; ++r) linv[r] = 1.0f / __shfl(lt, lg4 + r);
#pragma unroll
    for (int db = 0; db < 4; ++db)
#pragma unroll
      for (int r = 0; r < 4; ++r)
        aob[(size_t)(q0A + lg4 + r) * 1024 + db * 16 + lq] =
            (_Float16)(oA[db][r] * linv[r]);
  }
  {
    float lt = lBp + __shfl_xor(lBp, 16);
    lt += __shfl_xor(lt, 32);
    f32x4 linv;
#pragma unroll
    for (int r = 0; r < 4; ++r) linv[r] = 1.0f / __shfl(lt, lg4 + r);
#pragma unroll
    for (int db = 0; db < 4; ++db)
#pragma unroll
      for (int r = 0; r < 4; ++r)
        aob[(size_t)(q0B + lg4 + r) * 1024 + db * 16 + lq] =
            (_Float16)(oB[db][r] * linv[r]);
  }
}

// -------------------------------- launch ----------------------------------
extern "C" void kernel_launch(void* const* d_in, const int* in_sizes, int n_in,
                              void* d_out, int out_size, void* d_ws,
                              size_t ws_size, hipStream_t stream) {
  const float* x = (const float*)d_in[0];
  const float* qk_w = (const float*)d_in[1];
  const float* qk_b = (const float*)d_in[2];
  const float* v_w = (const float*)d_in[3];
  const float* v_b = (const float*)d_in[4];
  const float* out_w = (const float*)d_in[5];
  const float* out_b = (const float*)d_in[6];
  const float* bias = (const float*)d_in[7];
  float* out = (float*)d_out;

  // workspace (fp16 elems): xb 8M | wb 3M | owb 1M | qk 16M | vt 8M | ao 8M
  _Float16* xb = (_Float16*)d_ws;
  _Float16* wb = xb + (size_t)8388608;
  _Float16* owb = wb + (size_t)3145728;
  _Float16* qkbuf = owb + (size_t)1048576;
  _Float16* vtbuf = qkbuf + (size_t)16777216;
  _Float16* ao = vtbuf + (size_t)8388608;

  // all conversions in one launch
  cvt4_kernel<<<12288, 256, 0, stream>>>(x, qk_w, v_w, out_w, xb, wb,
                                         wb + 2097152, owb);

  // fused QKV projection: M=8192, N=3072 (2048 qk | 1024 v), K=1024
  gemm_kernel<0><<<dim3(24, 64), 256, 0, stream>>>(
      xb, wb, 8192, 3072, 1024, qk_b, v_b, qkbuf, vtbuf, nullptr, nullptr);

  // flash attention: 8 balanced blocks per (b,h)
  attn_kernel<<<1024, 256, 0, stream>>>(qkbuf, vtbuf, bias, ao);

  // output projection: M=8192, N=1024, K=1024 -> fp32 d_out
  gemm_kernel<1><<<dim3(8, 64), 256, 0, stream>>>(
      ao, owb, 8192, 1024, 1024, nullptr, nullptr, nullptr, nullptr, out_b, out);
}